// Round 1
// 100.677 us; speedup vs baseline: 1.0190x; 1.0190x over previous
//
#include <hip/hip_runtime.h>

#define LSEQ 4096
#define NT   1024                 // 1 float4 of cmap row per thread
#define IT   4                    // row-pairs per block (persistent-ish)
#define NBLK (LSEQ / (2 * IT))    // 512 blocks
#define FNT  256

#define IDEAL 6.0f
#define MIN_DIST 3.4f
#define TARGET 9.0f               // 1.5 * IDEAL
#define W_BOND 1.0f
#define W_CLASH 2.0f
#define W_PAIR 0.5f

// Session rules (carried forward):
// - NO atomics/fences in hot kernel (device-scope fence = per-XCD L2 writeback,
//   2048 of them ~ 100us, R3-R5).
// - NO runtime-indexed per-thread arrays that survive unrolling (rule #20):
//   all arrays below have compile-time indices after #pragma unroll.
// - Raw v_sqrt_f32 via __builtin_amdgcn_sqrtf (libm fixup was ~1/3 of VALU, R8).
// R11 (this round): persistent blocks over IT=4 row-pairs with cross-iteration
// register prefetch of the cmap stream. Rationale: old burst-then-drain per-block
// structure left the HBM stream idle during compute phases and paid 2048 cold
// start latencies; this issues loads continuously and holds j-coords in regs
// across iterations. Target: er_pair at cmap-stream roofline (~13 us).

__global__ __launch_bounds__(NT) void er_pair(
        const float* __restrict__ coords,
        const float* __restrict__ cmap,
        float4* __restrict__ ws) {
    const int t = threadIdx.x;
    const int b = blockIdx.x;

    const float4* cp4 = (const float4*)coords;
    const float4* cm4 = (const float4*)cmap;     // row r: cm4[r*(LSEQ/4) + t]

    // ---- j-side coords: 4 columns per thread, loaded ONCE, live all IT iters
    const float4 A = cp4[3 * t + 0];
    const float4 B = cp4[3 * t + 1];
    const float4 C = cp4[3 * t + 2];

    // ---- wave-uniform i-side coords for all IT row-pairs (scalar loads, hoisted)
    float xi0[IT], yi0[IT], zi0[IT], xi1[IT], yi1[IT], zi1[IT];
#pragma unroll
    for (int k = 0; k < IT; ++k) {
        const int i0 = 2 * (b + k * NBLK);
        xi0[k] = coords[3 * i0 + 0];
        yi0[k] = coords[3 * i0 + 1];
        zi0[k] = coords[3 * i0 + 2];
        xi1[k] = coords[3 * i0 + 3];   // row i0+1
        yi1[k] = coords[3 * i0 + 4];
        zi1[k] = coords[3 * i0 + 5];
    }

    float cl0 = 0.0f, cl1 = 0.0f;
    float pr0 = 0.0f, pr1 = 0.0f;
    float ct0 = 0.0f, ct1 = 0.0f;

    const int j0 = 4 * t;

#define ROWIDX(k, r) ((size_t)(2 * (b + (k) * NBLK) + (r)) * (LSEQ / 4) + t)

#define COMP(kk, M0, M1)                                                      \
    do {                                                                      \
        const int i0 = 2 * (b + (kk) * NBLK);                                 \
        const float xs[4] = {A.x, A.w, B.z, C.y};                             \
        const float ys[4] = {A.y, B.x, B.w, C.z};                             \
        const float zs[4] = {A.z, B.y, C.x, C.w};                             \
        const float cv0[4] = {M0.x, M0.y, M0.z, M0.w};                        \
        const float cv1[4] = {M1.x, M1.y, M1.z, M1.w};                        \
        _Pragma("unroll")                                                     \
        for (int q = 0; q < 4; ++q) {                                         \
            const int sep0 = j0 + q - i0;  /* sep1 = sep0 - 1 */              \
            {   /* row 0 */                                                   \
                const float dx = xi0[kk] - xs[q];                             \
                const float dy = yi0[kk] - ys[q];                             \
                const float dz = zi0[kk] - zs[q];                             \
                const float d2 = fmaf(dx, dx, fmaf(dy, dy, dz * dz));         \
                const float d = __builtin_amdgcn_sqrtf(d2);                   \
                float cl = fmaxf(MIN_DIST - d, 0.0f);                         \
                cl = (sep0 >= 3) ? cl : 0.0f;                                 \
                cl0 = fmaf(cl, cl, cl0);                                      \
                const float pdm = ((unsigned int)(sep0 + 2) > 4u)             \
                                      ? (d - TARGET) : 0.0f;                  \
                pr0 = fmaf(cv0[q] * pdm, pdm, pr0);                           \
                ct0 += cv0[q];                                                \
            }                                                                 \
            {   /* row 1 */                                                   \
                const float dx = xi1[kk] - xs[q];                             \
                const float dy = yi1[kk] - ys[q];                             \
                const float dz = zi1[kk] - zs[q];                             \
                const float d2 = fmaf(dx, dx, fmaf(dy, dy, dz * dz));         \
                const float d = __builtin_amdgcn_sqrtf(d2);                   \
                float cl = fmaxf(MIN_DIST - d, 0.0f);                         \
                cl = (sep0 >= 4) ? cl : 0.0f;                                 \
                cl1 = fmaf(cl, cl, cl1);                                      \
                const float pdm = ((unsigned int)(sep0 + 1) > 4u)             \
                                      ? (d - TARGET) : 0.0f;                  \
                pr1 = fmaf(cv1[q] * pdm, pdm, pr1);                           \
                ct1 += cv1[q];                                                \
            }                                                                 \
        }                                                                     \
    } while (0)

    // ---- software pipeline over IT row-pairs: depth-2 at start, depth-1 steady.
    // cmap loads for pair k+1 are in flight while pair k computes.
    float4 mA0 = cm4[ROWIDX(0, 0)], mA1 = cm4[ROWIDX(0, 1)];
    float4 mB0 = cm4[ROWIDX(1, 0)], mB1 = cm4[ROWIDX(1, 1)];

    COMP(0, mA0, mA1);
    mA0 = cm4[ROWIDX(2, 0)]; mA1 = cm4[ROWIDX(2, 1)];
    COMP(1, mB0, mB1);
    mB0 = cm4[ROWIDX(3, 0)]; mB1 = cm4[ROWIDX(3, 1)];
    COMP(2, mA0, mA1);
    COMP(3, mB0, mB1);

#undef COMP
#undef ROWIDX

    float clash_acc = cl0 + cl1;
    float pair_acc = pr0 + pr1;
    float cnt_acc = ct0 + ct1;

#pragma unroll
    for (int off = 32; off > 0; off >>= 1) {
        clash_acc += __shfl_down(clash_acc, off);
        pair_acc  += __shfl_down(pair_acc, off);
        cnt_acc   += __shfl_down(cnt_acc, off);
    }
    __shared__ float s_clash[NT / 64], s_pair[NT / 64], s_cnt[NT / 64];
    const int wave = t >> 6;
    const int lane = t & 63;
    if (lane == 0) { s_clash[wave] = clash_acc; s_pair[wave] = pair_acc; s_cnt[wave] = cnt_acc; }
    __syncthreads();
    if (t == 0) {
        float cs = 0.0f, ps = 0.0f, ns = 0.0f;
#pragma unroll
        for (int w = 0; w < NT / 64; ++w) { cs += s_clash[w]; ps += s_pair[w]; ns += s_cnt[w]; }
        ws[b] = make_float4(cs, ps, ns, 0.0f);   // one slot write: no atomics/fences
    }
}

__global__ __launch_bounds__(FNT) void er_finalize(
        const float* __restrict__ coords,
        const float4* __restrict__ ws,
        float* __restrict__ out) {
    const int t = threadIdx.x;
    float cs = 0.0f, ps = 0.0f, ns = 0.0f;
    for (int idx = t; idx < NBLK; idx += FNT) {
        const float4 v = ws[idx];
        cs += v.x; ps += v.y; ns += v.z;
    }
    // bond term
    float bacc = 0.0f;
    for (int s = t; s < LSEQ - 1; s += FNT) {
        const float dx = coords[3 * (s + 1) + 0] - coords[3 * s + 0];
        const float dy = coords[3 * (s + 1) + 1] - coords[3 * s + 1];
        const float dz = coords[3 * (s + 1) + 2] - coords[3 * s + 2];
        const float d = __builtin_amdgcn_sqrtf(fmaf(dx, dx, fmaf(dy, dy, dz * dz)));
        const float e = d - IDEAL;
        bacc += e * e;
    }
#pragma unroll
    for (int off = 32; off > 0; off >>= 1) {
        cs += __shfl_down(cs, off);
        ps += __shfl_down(ps, off);
        ns += __shfl_down(ns, off);
        bacc += __shfl_down(bacc, off);
    }
    __shared__ float sc[FNT / 64], sp[FNT / 64], sn[FNT / 64], sb[FNT / 64];
    const int wave = t >> 6;
    const int lane = t & 63;
    if (lane == 0) { sc[wave] = cs; sp[wave] = ps; sn[wave] = ns; sb[wave] = bacc; }
    __syncthreads();
    if (t == 0) {
        float tc = 0.0f, tp = 0.0f, tn = 0.0f, tb = 0.0f;
#pragma unroll
        for (int w = 0; w < FNT / 64; ++w) { tc += sc[w]; tp += sp[w]; tn += sn[w]; tb += sb[w]; }
        const float e_bond = tb / (float)(LSEQ - 1);
        const float e_clash = tc / (float)LSEQ;
        const float e_pair = tp / fmaxf(tn, 1.0f);
        out[0] = W_BOND * e_bond + W_CLASH * e_clash + W_PAIR * e_pair;
    }
}

extern "C" void kernel_launch(void* const* d_in, const int* in_sizes, int n_in,
                              void* d_out, int out_size, void* d_ws, size_t ws_size,
                              hipStream_t stream) {
    const float* coords = (const float*)d_in[0];
    const float* cmap   = (const float*)d_in[1];
    float4* ws = (float4*)d_ws;
    float* out = (float*)d_out;

    hipLaunchKernelGGL(er_pair, dim3(NBLK), dim3(NT), 0, stream, coords, cmap, ws);
    hipLaunchKernelGGL(er_finalize, dim3(1), dim3(FNT), 0, stream, coords, ws, out);
}

// Round 2
// 99.290 us; speedup vs baseline: 1.0332x; 1.0140x over previous
//
#include <hip/hip_runtime.h>

#define LSEQ 4096
#define NT   1024                 // 1 float4 of each cmap row per thread
#define IT   8                    // row-pairs per block
#define NBLK (LSEQ / (2 * IT))    // 256 blocks = exactly 1 per CU
#define FNT  256

#define IDEAL 6.0f
#define MIN_DIST 3.4f
#define TARGET 9.0f               // 1.5 * IDEAL
#define W_BOND 1.0f
#define W_CLASH 2.0f
#define W_PAIR 0.5f

// Session rules (carried forward):
// - NO atomics/fences in hot kernel (device-scope fence = per-XCD L2 writeback,
//   2048 of them ~ 100us, R3-R5).
// - NO runtime-indexed per-thread arrays that survive unrolling (rule #20):
//   all arrays below unroll to compile-time indices; cmap prefetch uses NAMED
//   float4 slots in a rotating 3-pair pipeline.
// - Raw v_sqrt_f32 via __builtin_amdgcn_sqrtf (libm fixup was ~1/3 of VALU, R8).
// R12 (this round): decisive floor-push. 256 blocks (1/CU, no tail, no 2nd
// block generation), IT=8 row-pairs with 3-pair-deep rotating prefetch
// (6 float4 = 96B/lane in flight, ~96KB/CU >> 22KB BW*latency product).
// Bond term folded into er_pair (16 threads/block, L2-hot coords) so
// er_finalize is a bare 4KB reduction. If dur_us stays ~97+: the remaining
// time is the harness 256MiB ws-poison stream (42us @ 80% HBM) -> roofline.

__global__ __launch_bounds__(NT) void er_pair(
        const float* __restrict__ coords,
        const float* __restrict__ cmap,
        float4* __restrict__ ws) {
    const int t = threadIdx.x;
    const int b = blockIdx.x;

    const float4* cp4 = (const float4*)coords;
    const float4* cm4 = (const float4*)cmap;     // row r: cm4[r*(LSEQ/4) + t]

    // ---- j-side coords: 4 columns per thread, loaded ONCE, live all IT iters
    const float4 A = cp4[3 * t + 0];
    const float4 B = cp4[3 * t + 1];
    const float4 C = cp4[3 * t + 2];

    // ---- wave-uniform i-side coords for all IT row-pairs (scalar/SGPR loads)
    float xi0[IT], yi0[IT], zi0[IT], xi1[IT], yi1[IT], zi1[IT];
#pragma unroll
    for (int k = 0; k < IT; ++k) {
        const int i0 = 2 * (b + k * NBLK);
        xi0[k] = coords[3 * i0 + 0];
        yi0[k] = coords[3 * i0 + 1];
        zi0[k] = coords[3 * i0 + 2];
        xi1[k] = coords[3 * i0 + 3];   // row i0+1
        yi1[k] = coords[3 * i0 + 4];
        zi1[k] = coords[3 * i0 + 5];
    }

    float cl0 = 0.0f, cl1 = 0.0f;
    float pr0 = 0.0f, pr1 = 0.0f;
    float ct0 = 0.0f, ct1 = 0.0f;

    const int j0 = 4 * t;

#define RIDX(k, r) ((size_t)(2 * (b + (k) * NBLK) + (r)) * (LSEQ / 4) + t)

#define COMP(kk, M0, M1)                                                      \
    do {                                                                      \
        const int i0 = 2 * (b + (kk) * NBLK);                                 \
        const float xs[4] = {A.x, A.w, B.z, C.y};                             \
        const float ys[4] = {A.y, B.x, B.w, C.z};                             \
        const float zs[4] = {A.z, B.y, C.x, C.w};                             \
        const float cv0[4] = {M0.x, M0.y, M0.z, M0.w};                        \
        const float cv1[4] = {M1.x, M1.y, M1.z, M1.w};                        \
        _Pragma("unroll")                                                     \
        for (int q = 0; q < 4; ++q) {                                         \
            const int sep0 = j0 + q - i0;  /* sep1 = sep0 - 1 */              \
            {   /* row 0 */                                                   \
                const float dx = xi0[kk] - xs[q];                             \
                const float dy = yi0[kk] - ys[q];                             \
                const float dz = zi0[kk] - zs[q];                             \
                const float d2 = fmaf(dx, dx, fmaf(dy, dy, dz * dz));         \
                const float d = __builtin_amdgcn_sqrtf(d2);                   \
                float cl = fmaxf(MIN_DIST - d, 0.0f);                         \
                cl = (sep0 >= 3) ? cl : 0.0f;                                 \
                cl0 = fmaf(cl, cl, cl0);                                      \
                const float pdm = ((unsigned int)(sep0 + 2) > 4u)             \
                                      ? (d - TARGET) : 0.0f;                  \
                pr0 = fmaf(cv0[q] * pdm, pdm, pr0);                           \
                ct0 += cv0[q];                                                \
            }                                                                 \
            {   /* row 1 */                                                   \
                const float dx = xi1[kk] - xs[q];                             \
                const float dy = yi1[kk] - ys[q];                             \
                const float dz = zi1[kk] - zs[q];                             \
                const float d2 = fmaf(dx, dx, fmaf(dy, dy, dz * dz));         \
                const float d = __builtin_amdgcn_sqrtf(d2);                   \
                float cl = fmaxf(MIN_DIST - d, 0.0f);                         \
                cl = (sep0 >= 4) ? cl : 0.0f;                                 \
                cl1 = fmaf(cl, cl, cl1);                                      \
                const float pdm = ((unsigned int)(sep0 + 1) > 4u)             \
                                      ? (d - TARGET) : 0.0f;                  \
                pr1 = fmaf(cv1[q] * pdm, pdm, pr1);                           \
                ct1 += cv1[q];                                                \
            }                                                                 \
        }                                                                     \
    } while (0)

    // ---- rotating 3-pair-deep prefetch over IT=8 row-pairs.
    // 6 float4 (96B/lane) continuously outstanding; M-regs die at COMP entry
    // (cv extraction), so the reload issues immediately under the compute.
    float4 m0a = cm4[RIDX(0, 0)], m0b = cm4[RIDX(0, 1)];
    float4 m1a = cm4[RIDX(1, 0)], m1b = cm4[RIDX(1, 1)];
    float4 m2a = cm4[RIDX(2, 0)], m2b = cm4[RIDX(2, 1)];

    COMP(0, m0a, m0b); m0a = cm4[RIDX(3, 0)]; m0b = cm4[RIDX(3, 1)];
    COMP(1, m1a, m1b); m1a = cm4[RIDX(4, 0)]; m1b = cm4[RIDX(4, 1)];
    COMP(2, m2a, m2b); m2a = cm4[RIDX(5, 0)]; m2b = cm4[RIDX(5, 1)];
    COMP(3, m0a, m0b); m0a = cm4[RIDX(6, 0)]; m0b = cm4[RIDX(6, 1)];
    COMP(4, m1a, m1b); m1a = cm4[RIDX(7, 0)]; m1b = cm4[RIDX(7, 1)];
    COMP(5, m2a, m2b);
    COMP(6, m0a, m0b);
    COMP(7, m1a, m1b);

#undef COMP
#undef RIDX

    // ---- bond partial: 16 bonds per block, threads t<16, coords L2-hot by now
    float bacc = 0.0f;
    if (t < 16) {
        const int s = 16 * b + t;
        if (s < LSEQ - 1) {
            const float dx = coords[3 * (s + 1) + 0] - coords[3 * s + 0];
            const float dy = coords[3 * (s + 1) + 1] - coords[3 * s + 1];
            const float dz = coords[3 * (s + 1) + 2] - coords[3 * s + 2];
            const float d = __builtin_amdgcn_sqrtf(fmaf(dx, dx, fmaf(dy, dy, dz * dz)));
            const float e = d - IDEAL;
            bacc = e * e;
        }
    }

    float clash_acc = cl0 + cl1;
    float pair_acc = pr0 + pr1;
    float cnt_acc = ct0 + ct1;

#pragma unroll
    for (int off = 32; off > 0; off >>= 1) {
        clash_acc += __shfl_down(clash_acc, off);
        pair_acc  += __shfl_down(pair_acc, off);
        cnt_acc   += __shfl_down(cnt_acc, off);
        bacc      += __shfl_down(bacc, off);
    }
    __shared__ float s_clash[NT / 64], s_pair[NT / 64], s_cnt[NT / 64], s_bond[NT / 64];
    const int wave = t >> 6;
    const int lane = t & 63;
    if (lane == 0) { s_clash[wave] = clash_acc; s_pair[wave] = pair_acc;
                     s_cnt[wave] = cnt_acc;     s_bond[wave] = bacc; }
    __syncthreads();
    if (t == 0) {
        float cs = 0.0f, ps = 0.0f, ns = 0.0f, bs = 0.0f;
#pragma unroll
        for (int w = 0; w < NT / 64; ++w) {
            cs += s_clash[w]; ps += s_pair[w]; ns += s_cnt[w]; bs += s_bond[w];
        }
        ws[b] = make_float4(cs, ps, ns, bs);   // one slot write: no atomics/fences
    }
}

__global__ __launch_bounds__(FNT) void er_finalize(
        const float4* __restrict__ ws,
        float* __restrict__ out) {
    const int t = threadIdx.x;
    // NBLK == FNT: one slot per thread
    const float4 v = ws[t];
    float cs = v.x, ps = v.y, ns = v.z, bs = v.w;
#pragma unroll
    for (int off = 32; off > 0; off >>= 1) {
        cs += __shfl_down(cs, off);
        ps += __shfl_down(ps, off);
        ns += __shfl_down(ns, off);
        bs += __shfl_down(bs, off);
    }
    __shared__ float sc[FNT / 64], sp[FNT / 64], sn[FNT / 64], sb[FNT / 64];
    const int wave = t >> 6;
    const int lane = t & 63;
    if (lane == 0) { sc[wave] = cs; sp[wave] = ps; sn[wave] = ns; sb[wave] = bs; }
    __syncthreads();
    if (t == 0) {
        float tc = 0.0f, tp = 0.0f, tn = 0.0f, tb = 0.0f;
#pragma unroll
        for (int w = 0; w < FNT / 64; ++w) { tc += sc[w]; tp += sp[w]; tn += sn[w]; tb += sb[w]; }
        const float e_bond = tb / (float)(LSEQ - 1);
        const float e_clash = tc / (float)LSEQ;
        const float e_pair = tp / fmaxf(tn, 1.0f);
        out[0] = W_BOND * e_bond + W_CLASH * e_clash + W_PAIR * e_pair;
    }
}

extern "C" void kernel_launch(void* const* d_in, const int* in_sizes, int n_in,
                              void* d_out, int out_size, void* d_ws, size_t ws_size,
                              hipStream_t stream) {
    const float* coords = (const float*)d_in[0];
    const float* cmap   = (const float*)d_in[1];
    float4* ws = (float4*)d_ws;
    float* out = (float*)d_out;

    hipLaunchKernelGGL(er_pair, dim3(NBLK), dim3(NT), 0, stream, coords, cmap, ws);
    hipLaunchKernelGGL(er_finalize, dim3(1), dim3(FNT), 0, stream, ws, out);
}